// Round 7
// baseline (3036.602 us; speedup 1.0000x reference)
//
#include <hip/hip_runtime.h>
#include <hip/hip_bf16.h>

// LSTM B=1024 T=256 IN=64 H=512. Round 7: persistent kernel, plain launch.
// vs R6 (1881us): the per-step m-group BARRIER chain (atomic add + poll +
// full serialization of load->compute->store) is replaced by per-producer
// DATAFLOW FLAGS: producer jb of group g publishes done[g][jb]=t+1 after
// its h stores drain (syncthreads emits vmcnt(0) before s_barrier); each
// consumer polls all 8 flags of its group in ONE wave-load (lane tid&7
// reads flag tid&7, 64B line) and proceeds when __any(flag<t)==0.
// 3-buffer rotation + monotone flags bound intra-group skew to <=1 step
// (writer of buffer t%3 at step t+3 requires done>=t+3 => readers of that
// buffer at step t+1 are finished). Bias folded into MFMA acc init.
// Weights f16 register-resident, c in registers, DPP epilogue.

#define TST   256
#define BATCH 1024
#define HID   512
#define INSZ  64
#define NCLS  10
#define LDSTR 584   // elem stride: 1168 B; measured conflict cost ~1.5% (R6) — acceptable

typedef _Float16 f16x8  __attribute__((ext_vector_type(8)));
typedef float    f32x16 __attribute__((ext_vector_type(16)));
typedef unsigned long long u64;

__device__ __forceinline__ float tanh_f(float x) {
    return 2.0f / (1.0f + __expf(-2.0f * x)) - 1.0f;
}

__device__ __forceinline__ f16x8 cvt8(float4 a, float4 b) {
    f16x8 o;
    o[0] = (_Float16)a.x; o[1] = (_Float16)a.y; o[2] = (_Float16)a.z; o[3] = (_Float16)a.w;
    o[4] = (_Float16)b.x; o[5] = (_Float16)b.y; o[6] = (_Float16)b.z; o[7] = (_Float16)b.w;
    return o;
}

template <int CTRL>
__device__ __forceinline__ float dpp_f(float v) {
    return __builtin_bit_cast(float,
        __builtin_amdgcn_mov_dpp(__builtin_bit_cast(int, v), CTRL, 0xF, 0xF, true));
}
template <int CTRL>
__device__ __forceinline__ unsigned dpp_u(unsigned v) {
    return (unsigned)__builtin_amdgcn_mov_dpp((int)v, CTRL, 0xF, 0xF, true);
}
// quad_perm xor1=0xB1, xor2=0x4E, xor3=0x1B; row_shl:4=0x104, row_shl:8=0x108

__global__ __launch_bounds__(256, 1) void lstm_persist(
    const float* __restrict__ x,   const float* __restrict__ h0,
    const float* __restrict__ c0,  const float* __restrict__ Wih,
    const float* __restrict__ Whh, const float* __restrict__ bih,
    const float* __restrict__ bhh, _Float16* __restrict__ hb,
    unsigned* __restrict__ done)
{
    __shared__ __align__(16) _Float16 As[32][LDSTR];   // 37376 B

    const int tid   = threadIdx.x;
    const int lane  = tid & 63;
    const int w     = tid >> 6;        // wave 0..3
    const int l31   = lane & 31;
    const int khalf = (lane >> 5) * 8;
    const int g  = (int)(blockIdx.x >> 3);   // m-group 0..31
    const int jb = (int)(blockIdx.x & 7);    // j-block 0..7
    const int m0 = g * 32;
    const int j0 = jb * 64;
    unsigned* gflags = done + g * 16;        // 8 flags on one 64B line per group

    const int gate = l31 & 3;                // nt*32 preserves np&3
    int jcol[2], nrow[2];
    #pragma unroll
    for (int nt = 0; nt < 2; ++nt) {
        int np = w * 64 + nt * 32 + l31;
        jcol[nt] = j0 + (np >> 2);
        nrow[nt] = gate * HID + jcol[nt];
    }

    // ---- B fragments in registers (one-time): bfr[nt][kt] ----
    f16x8 bfr[2][36];
    #pragma unroll
    for (int nt = 0; nt < 2; ++nt)
        #pragma unroll
        for (int kt = 0; kt < 36; ++kt) {
            const int k0 = kt * 16 + khalf;
            const float* p = (kt < 32) ? (Whh + (size_t)nrow[nt] * HID + k0)
                                       : (Wih + (size_t)nrow[nt] * INSZ + (k0 - HID));
            float4 f0 = ((const float4*)p)[0];
            float4 f1 = ((const float4*)p)[1];
            bfr[nt][kt] = cvt8(f0, f1);
        }
    float bsv[2];
    bsv[0] = bih[nrow[0]] + bhh[nrow[0]];
    bsv[1] = bih[nrow[1]] + bhh[nrow[1]];
    const float s   = (gate == 2) ? 2.0f : 1.0f;   // tanh for g, sigmoid otherwise
    const int rowhi = (lane >> 5) * 4;

    // ---- c state in registers (lead lanes l31%4==0 hold the real values) ----
    float cr[2][16];
    #pragma unroll
    for (int nt = 0; nt < 2; ++nt)
        #pragma unroll
        for (int r = 0; r < 16; ++r) {
            int row = (r & 3) + 8 * (r >> 2) + rowhi;
            cr[nt][r] = c0[(size_t)(m0 + row) * HID + jcol[nt]];
        }

    const int rr8 = tid >> 3;      // staging: 8 threads per row (32 rows)
    const int q8  = tid & 7;       // 16B per thread per 64-col slice
    const int myp = tid & 7;       // flag index this thread polls

    for (int t = 0; t < TST; ++t) {
        const _Float16* rb = hb + (size_t)((t + 2) % 3) * (BATCH * HID);
        _Float16*       wb = hb + (size_t)(t % 3) * (BATCH * HID);

        // ---- x_t loads first (independent of recurrence) ----
        float4 x0, x1;
        {
            const float* xp = x + (size_t)(m0 + rr8) * (TST * INSZ) + t * INSZ + q8 * 8;
            x0 = ((const float4*)xp)[0];
            x1 = ((const float4*)xp)[1];
        }

        if (t == 0) {
            #pragma unroll
            for (int p = 0; p < 8; ++p) {
                const float* hp = h0 + (size_t)(m0 + rr8) * HID + p * 64 + q8 * 8;
                float4 f0 = ((const float4*)hp)[0];
                float4 f1 = ((const float4*)hp)[1];
                *(f16x8*)&As[rr8][p * 64 + q8 * 8] = cvt8(f0, f1);
            }
        } else {
            // ---- concurrent 8-flag poll: one coherent wave-load per round ----
            while (1) {
                unsigned fl = __hip_atomic_load(&gflags[myp],
                                                __ATOMIC_RELAXED, __HIP_MEMORY_SCOPE_AGENT);
                if (!__any((int)fl < t)) break;
                __builtin_amdgcn_s_sleep(1);
            }
            // ---- issue ALL 16 coherent 8B loads (8 slices x 16B/thread) ----
            const u64* rbq = (const u64*)(rb + (size_t)(m0 + rr8) * HID);
            u64 hv[16];
            #pragma unroll
            for (int p = 0; p < 8; ++p) {
                hv[2 * p]     = __hip_atomic_load(&rbq[p * 16 + q8 * 2],
                                   __ATOMIC_RELAXED, __HIP_MEMORY_SCOPE_AGENT);
                hv[2 * p + 1] = __hip_atomic_load(&rbq[p * 16 + q8 * 2 + 1],
                                   __ATOMIC_RELAXED, __HIP_MEMORY_SCOPE_AGENT);
            }
            #pragma unroll
            for (int p = 0; p < 8; ++p) {
                *(u64*)&As[rr8][p * 64 + q8 * 8]     = hv[2 * p];
                *(u64*)&As[rr8][p * 64 + q8 * 8 + 4] = hv[2 * p + 1];
            }
        }
        *(f16x8*)&As[rr8][512 + q8 * 8] = cvt8(x0, x1);   // x_t -> k 512..575
        __syncthreads();

        // ---- MFMA: 36 k-tiles, bias pre-loaded into acc, 1 A-read / 2 MFMA ----
        f32x16 acc[2];
        #pragma unroll
        for (int i = 0; i < 16; ++i) { acc[0][i] = bsv[0]; acc[1][i] = bsv[1]; }
        #pragma unroll
        for (int kt = 0; kt < 36; ++kt) {
            f16x8 af = *(const f16x8*)&As[l31][kt * 16 + khalf];
            acc[0] = __builtin_amdgcn_mfma_f32_32x32x16_f16(af, bfr[0][kt], acc[0], 0, 0, 0);
            acc[1] = __builtin_amdgcn_mfma_f32_32x32x16_f16(af, bfr[1][kt], acc[1], 0, 0, 0);
        }

        // ---- epilogue: DPP gate combine, c/h update, packed 8B coherent stores
        #pragma unroll
        for (int nt = 0; nt < 2; ++nt) {
            #pragma unroll
            for (int r = 0; r < 16; ++r) {
                float v = acc[nt][r];
                float e = __expf(-s * v);
                float act = s / (1.0f + e) - (s - 1.0f);   // sigmoid or tanh
                float fu = dpp_f<0xB1>(act);   // quad xor1: f
                float gu = dpp_f<0x4E>(act);   // quad xor2: g
                float ou = dpp_f<0x1B>(act);   // quad xor3: o
                float cn = fu * cr[nt][r] + act * gu;
                cr[nt][r] = cn;
                float hn = ou * tanh_f(cn);
                unsigned hu = (unsigned)__builtin_bit_cast(unsigned short, (_Float16)hn);
                unsigned pk = hu | (dpp_u<0x104>(hu) << 16);          // <- lane+4
                u64 v4 = (u64)pk | ((u64)dpp_u<0x108>(pk) << 32);     // <- lane+8
                if ((l31 & 15) == 0) {
                    int row = (r & 3) + 8 * (r >> 2) + rowhi;
                    __hip_atomic_store((u64*)&wb[(size_t)(m0 + row) * HID + jcol[nt]],
                                       v4, __ATOMIC_RELAXED, __HIP_MEMORY_SCOPE_AGENT);
                }
            }
        }

        // ---- publish: syncthreads drains all waves' vmcnt, then flag store ----
        __syncthreads();
        if (tid == 0)
            __hip_atomic_store(&gflags[jb], (unsigned)(t + 1),
                               __ATOMIC_RELEASE, __HIP_MEMORY_SCOPE_AGENT);
        // no trailing barrier: next iteration's flag poll is the sync point;
        // LDS WAR is protected by the syncthreads above (reads precede it).
    }
}

// ---------------- final linear: preds = hT @ W_lin^T + b_lin ----------------
__global__ __launch_bounds__(256) void final_kernel(
    const _Float16* __restrict__ h, const float* __restrict__ Wl,
    const float* __restrict__ bl, float* __restrict__ out)
{
    int i = blockIdx.x * 256 + threadIdx.x;
    if (i >= BATCH * NCLS) return;
    int b = i / NCLS, c = i - b * NCLS;
    const f16x8* hp = (const f16x8*)(h + (size_t)b * HID);
    const float4* wp = (const float4*)(Wl + (size_t)c * HID);
    float sacc = bl[c];
    #pragma unroll 4
    for (int k8 = 0; k8 < HID / 8; ++k8) {
        f16x8 hv = hp[k8];
        float4 w0 = wp[2 * k8], w1 = wp[2 * k8 + 1];
        sacc += (float)hv[0] * w0.x + (float)hv[1] * w0.y +
                (float)hv[2] * w0.z + (float)hv[3] * w0.w +
                (float)hv[4] * w1.x + (float)hv[5] * w1.y +
                (float)hv[6] * w1.z + (float)hv[7] * w1.w;
    }
    out[i] = sacc;
}

extern "C" void kernel_launch(void* const* d_in, const int* in_sizes, int n_in,
                              void* d_out, int out_size, void* d_ws, size_t ws_size,
                              hipStream_t stream)
{
    const float* x    = (const float*)d_in[0];
    const float* h0   = (const float*)d_in[1];
    const float* c0   = (const float*)d_in[2];
    const float* Wih  = (const float*)d_in[3];
    const float* Whh  = (const float*)d_in[4];
    const float* bih  = (const float*)d_in[5];
    const float* bhh  = (const float*)d_in[6];
    const float* Wlin = (const float*)d_in[7];
    const float* blin = (const float*)d_in[8];
    float* out = (float*)d_out;

    unsigned* done = (unsigned*)d_ws;                  // 32 groups x 16 u32 (64B/group)
    _Float16* hb   = (_Float16*)((char*)d_ws + 8192);  // 3 x 1 MB h buffers

    hipMemsetAsync(d_ws, 0, 8192, stream);             // zero flags

    // 256 blocks, 1/CU (launch_bounds(256,1), 37KB LDS) -> all co-resident.
    lstm_persist<<<256, 256, 0, stream>>>(x, h0, c0, Wih, Whh, bih, bhh, hb, done);

    // step t=255 wrote buffer (255 % 3) == 0 -> hb
    final_kernel<<<(BATCH * NCLS + 255) / 256, 256, 0, stream>>>(hb, Wlin, blin, out);
}